// Round 10
// baseline (388.707 us; speedup 1.0000x reference)
//
#include <hip/hip_runtime.h>
#include <math.h>

// N=64, C=256, T=64, V=25 graph-ODE, 4 fused blocks. bf16 MFMA 32x32x16.
// R7: best 2-phase structure: 181.5us. R13: big-GEMM-first (out=A·(w·res)),
//     correct but 216us. Diagnosis: ALL structures ~95% stall -> per-wave ILP
//     too thin (1 ds-fed chain/wave) + w streamed 512KB/WG from L2 (2GB total).
// R14: S=2 TIME-SLABS PER WG. t and t+1 share w -> interleave both slabs in
//     the k-loop sharing wA/wB regs: 4 indep MFMA chains/iter (depth-4 w
//     rotation now spans ~240cy >= L2 latency), af ring issues 2 iters ahead
//     (>= LDS latency). w L2 traffic halves (2048 WGs). 4 accumulators =
//     64 AGPR -> 3 waves/SIMD via __launch_bounds__(256,3) (looser bound,
//     no forced-cap miscompile risk). In-place residual (unique (v,o) lane
//     ownership), 2 barriers/block.
#define NN 64
#define CC 256
#define TT 64
#define VV 25

typedef __bf16 bf16;
typedef __attribute__((ext_vector_type(8)))  __bf16 bf16x8;
typedef __attribute__((ext_vector_type(16))) float  f32x16;
typedef __attribute__((ext_vector_type(4)))  unsigned int uint4v;

#define RST 266   // sresT row stride (bf16): 532 B -> bank stride 5 (gcd(5,32)=1)

// Manual LDS layout (bytes).
#define OFF_SA    0        // slab0 res^T [u(32)][RST]: 17024
#define OFF_SB    17024    // slab1 res^T: 17024
#define OFF_SAB   34048    // A zero-padded 32x32: 2048
#define OFF_SBIAS 36096    // 4*256*4 = 4096
#define SMEM_BYTES 40192

// ---- pack the four 256x256 fp32 w into bf16 MFMA fragment order (R0-R7
//      verbatim; verified). Used as B-operand: B[kk][n] = w[o=n][c=kk]. ----
__global__ void convert_w(const float* __restrict__ w1, const float* __restrict__ w2,
                          const float* __restrict__ w3, const float* __restrict__ w4,
                          bf16* __restrict__ wp) {
    const int gid = blockIdx.x * 256 + threadIdx.x;   // 0..32767
    const int e8  = gid * 8;
    const int blk = e8 >> 16;
    const int off = e8 & 65535;
    const int row = off >> 8;
    const int col = off & 255;
    const float* src = (blk == 0) ? w1 : (blk == 1) ? w2 : (blk == 2) ? w3 : w4;
    const float4 f0 = *(const float4*)(src + off);
    const float4 f1 = *(const float4*)(src + off + 4);
    bf16x8 o;
    o[0] = (bf16)f0.x; o[1] = (bf16)f0.y; o[2] = (bf16)f0.z; o[3] = (bf16)f0.w;
    o[4] = (bf16)f1.x; o[5] = (bf16)f1.y; o[6] = (bf16)f1.z; o[7] = (bf16)f1.w;
    const int wv = row >> 6, pair = (row >> 5) & 1, l31 = row & 31;
    const int k = col >> 4, lh = (col >> 3) & 1;
    wp += (((size_t)(blk * 4 + wv) * 16 + k) * 1024) + pair * 512 + (lh * 32 + l31) * 8;
    *(bf16x8*)wp = o;
}

#define MFMA(A, B, C) __builtin_amdgcn_mfma_f32_32x32x16_bf16(A, B, C, 0, 0, 0)

static __device__ __forceinline__ unsigned int pkbf(float a, float b) {
    unsigned short lo = __builtin_bit_cast(unsigned short, (__bf16)a);
    unsigned short hi = __builtin_bit_cast(unsigned short, (__bf16)b);
    return (unsigned int)lo | ((unsigned int)hi << 16);
}

__global__ __launch_bounds__(256, 3) void ode_mfma(
    const float* __restrict__ x, const float* __restrict__ Amat,
    const bf16* __restrict__ wp,
    const float* __restrict__ b1, const float* __restrict__ b2,
    const float* __restrict__ b3, const float* __restrict__ b4,
    float* __restrict__ out)
{
    __shared__ __attribute__((aligned(16))) char smem[SMEM_BYTES];
    bf16*  sA    = (bf16*)(smem + OFF_SA);      // slab0 res^T
    bf16*  sB    = (bf16*)(smem + OFF_SB);      // slab1 res^T
    bf16*  sAb   = (bf16*)(smem + OFF_SAB);
    float* sbias = (float*)(smem + OFF_SBIAS);

    const int t0   = blockIdx.x * 2;
    const int t1   = t0 + 1;
    const int n    = blockIdx.y;
    const int tid  = threadIdx.x;
    const int wave = tid >> 6;
    const int lane = tid & 63;
    const int lh   = lane >> 5;
    const int l31  = lane & 31;
    const int o0   = wave * 64;

    // ---- blk0 w-prefetch (no LDS dependency; hides under staging) ----
    bf16x8 wA[4], wB[4];
    {
        const bf16* wb0 = wp + ((size_t)wave * 16) * 1024 + lane * 8;
        #pragma unroll
        for (int q = 0; q < 4; ++q) {
            wA[q] = *(const bf16x8*)(wb0 + q * 1024);
            wB[q] = *(const bf16x8*)(wb0 + q * 1024 + 512);
        }
    }

    // ---- stage biases ----
    sbias[0 * CC + tid] = b1[tid];
    sbias[1 * CC + tid] = b2[tid];
    sbias[2 * CC + tid] = b3[tid];
    sbias[3 * CC + tid] = b4[tid];

    // ---- stage A, zero-padded 32x32 ----
    for (int i = tid; i < 32 * 32; i += 256) {
        const int v = i >> 5, u = i & 31;
        sAb[i] = (v < VV && u < VV) ? (bf16)Amat[v * VV + u] : (bf16)0.f;
    }

    // ---- zero rows u=25..31 of both slabs (read by k-loop, never rewritten) ----
    for (int i = tid; i < 7 * 256; i += 256) {
        const int r = 25 + (i >> 8), c = i & 255;
        sA[r * RST + c] = (bf16)0.f;
        sB[r * RST + c] = (bf16)0.f;
    }

    // ---- stage both x slabs TRANSPOSED: s[v][c] = x[n,c,t,v] ----
    {
        const float* xb = x + ((size_t)n * CC * TT + t0) * VV;
        for (int i = tid; i < CC * VV; i += 256) {
            const int c = i / VV;
            const int v = i - c * VV;
            const float* p = xb + (size_t)c * TT * VV + v;
            sA[v * RST + c] = (bf16)p[0];
            sB[v * RST + c] = (bf16)p[VV];   // t1 = t0+1 -> +VV floats
        }
    }
    __syncthreads();

    // Amat A-fragments (rows v=l31, cols u = ks*16 + lh*8 + e).
    const bf16x8 bfA0 = *(const bf16x8*)&sAb[l31 * 32 + lh * 8];
    const bf16x8 bfA1 = *(const bf16x8*)&sAb[l31 * 32 + 16 + lh * 8];

    for (int blk = 0; blk < 4; ++blk) {
        const bf16* wbase = wp + ((size_t)(blk * 4 + wave) * 16) * 1024 + lane * 8;

        // ===== big GEMM both slabs: z[u,o] = sum_c resT[u,c]*w[o,c] =====
        f32x16 zA0 = {}, zA1 = {}, zB0 = {}, zB1 = {};
        bf16x8 afA[4], afB[4];
        afA[0] = *(const bf16x8*)&sA[l31 * RST + lh * 8];
        afB[0] = *(const bf16x8*)&sB[l31 * RST + lh * 8];
        afA[1] = *(const bf16x8*)&sA[l31 * RST + 16 + lh * 8];
        afB[1] = *(const bf16x8*)&sB[l31 * RST + 16 + lh * 8];

        #pragma unroll
        for (int k = 0; k < 16; ++k) {
            if (k + 2 < 16) {   // issue 2 iters ahead (~>=LDS latency)
                afA[(k + 2) & 3] = *(const bf16x8*)&sA[l31 * RST + (k + 2) * 16 + lh * 8];
                afB[(k + 2) & 3] = *(const bf16x8*)&sB[l31 * RST + (k + 2) * 16 + lh * 8];
            }
            const bf16x8 aA = afA[k & 3];
            const bf16x8 aB = afB[k & 3];
            zA0 = MFMA(aA, wA[k & 3], zA0);
            zB0 = MFMA(aB, wA[k & 3], zB0);
            zA1 = MFMA(aA, wB[k & 3], zA1);
            zB1 = MFMA(aB, wB[k & 3], zB1);
            if (k + 4 < 16) {   // depth-4 w rotation: ~240cy ahead of use now
                wA[k & 3] = *(const bf16x8*)(wbase + (k + 4) * 1024);
                wB[k & 3] = *(const bf16x8*)(wbase + (k + 4) * 1024 + 512);
            }
        }
        __syncthreads();   // barrier1: all k-loop reads done before any write

        // ---- prefetch next block's w: hides under mix+epilogue ----
        if (blk < 3) {
            const bf16* wn = wp + ((size_t)((blk + 1) * 4 + wave) * 16) * 1024 + lane * 8;
            #pragma unroll
            for (int q = 0; q < 4; ++q) {
                wA[q] = *(const bf16x8*)(wn + q * 1024);
                wB[q] = *(const bf16x8*)(wn + q * 1024 + 512);
            }
        }

        // ===== per tile: z (D-layout) -> B-frag (pack+permlane, R8-verified),
        //       A-mix (2 MFMAs), in-place residual epilogue =====
        #define FINAL_TILE(ZZ, SBUF, TSL, TL)                                       \
        {                                                                           \
            unsigned int a0 = pkbf(ZZ[0],  ZZ[1]),  a1 = pkbf(ZZ[2],  ZZ[3]);       \
            unsigned int a2 = pkbf(ZZ[4],  ZZ[5]),  a3 = pkbf(ZZ[6],  ZZ[7]);       \
            unsigned int a4 = pkbf(ZZ[8],  ZZ[9]),  a5 = pkbf(ZZ[10], ZZ[11]);      \
            unsigned int a6 = pkbf(ZZ[12], ZZ[13]), a7 = pkbf(ZZ[14], ZZ[15]);      \
            asm("v_permlane32_swap_b32 %0, %1" : "+v"(a0), "+v"(a2));               \
            asm("v_permlane32_swap_b32 %0, %1" : "+v"(a1), "+v"(a3));               \
            asm("v_permlane32_swap_b32 %0, %1" : "+v"(a4), "+v"(a6));               \
            asm("v_permlane32_swap_b32 %0, %1" : "+v"(a5), "+v"(a7));               \
            const bf16x8 y0 = __builtin_bit_cast(bf16x8, (uint4v){a0, a1, a2, a3}); \
            const bf16x8 y1 = __builtin_bit_cast(bf16x8, (uint4v){a4, a5, a6, a7}); \
            f32x16 d = {};                                                          \
            d = MFMA(bfA0, y0, d);                                                  \
            d = MFMA(bfA1, y1, d);                                                  \
            const int o = o0 + (TL) * 32 + l31;                                     \
            const float bb = sbias[blk * CC + o];                                   \
            _Pragma("unroll")                                                       \
            for (int q = 0; q < 16; ++q) {                                          \
                const int v = (q & 3) + 8 * (q >> 2) + 4 * lh;                      \
                float val = d[q] + bb + (float)SBUF[v * RST + o];                   \
                val = fmaxf(val, 0.f);                                              \
                if (v < VV) {                                                       \
                    if (blk < 3) SBUF[v * RST + o] = (bf16)val;                     \
                    else out[(((size_t)n * CC + o) * TT + (TSL)) * VV + v] = val;   \
                }                                                                   \
            }                                                                       \
        }
        FINAL_TILE(zA0, sA, t0, 0)
        FINAL_TILE(zA1, sA, t0, 1)
        FINAL_TILE(zB0, sB, t1, 0)
        FINAL_TILE(zB1, sB, t1, 1)
        #undef FINAL_TILE

        if (blk < 3) __syncthreads();   // barrier2: writes -> next k-loop reads
    }
}

extern "C" void kernel_launch(void* const* d_in, const int* in_sizes, int n_in,
                              void* d_out, int out_size, void* d_ws, size_t ws_size,
                              hipStream_t stream) {
    const float* x  = (const float*)d_in[1];
    const float* A  = (const float*)d_in[2];
    const float* w1 = (const float*)d_in[3];
    const float* b1 = (const float*)d_in[4];
    const float* w2 = (const float*)d_in[5];
    const float* b2 = (const float*)d_in[6];
    const float* w3 = (const float*)d_in[7];
    const float* b3 = (const float*)d_in[8];
    const float* w4 = (const float*)d_in[9];
    const float* b4 = (const float*)d_in[10];
    float* out = (float*)d_out;
    bf16* wp = (bf16*)d_ws;   // 512 KB packed w fragments

    convert_w<<<128, 256, 0, stream>>>(w1, w2, w3, w4, wp);
    dim3 grid(TT / 2, NN);    // one WG per (n, t-pair): 2048 WGs
    ode_mfma<<<grid, 256, 0, stream>>>(x, A, wp, b1, b2, b3, b4, out);
}

// Round 11
// 363.081 us; speedup vs baseline: 1.0706x; 1.0706x over previous
//
#include <hip/hip_runtime.h>
#include <math.h>

// N=64, C=256, T=64, V=25 graph-ODE, 4 fused blocks. bf16 MFMA 32x32x16.
// R7 (best, 181.5us): 2-phase structure, depth-4 w rotation, barrier after
//     k-loop, setprio around MFMA loop.
// R8-R14: structural alternatives all regressed (in-reg y 199, big-GEMM-first
//     216, S=2 slabs 233); occupancy pinned at ~4 WG/CU regardless of LDS.
// R15: R7 verbatim + w rotation depth 4->8 (+32 VGPR, total ~120 <= 128 at
//     4 waves/SIMD). Doubles L2-latency cover in the k-loop (~400cy >=
//     contended L2 latency); 8-slot next-block prefetch covers iters 0-7
//     of the following block's k-loop.
#define NN 64
#define CC 256
#define TT 64
#define VV 25

typedef __bf16 bf16;
typedef __attribute__((ext_vector_type(8)))  __bf16 bf16x8;
typedef __attribute__((ext_vector_type(4)))  __bf16 bf16x4;
typedef __attribute__((ext_vector_type(16))) float  f32x16;

#define RS 40    // sres row stride (bf16): 80 B
#define YS 264   // syT row stride (bf16): 528 B

// Manual LDS layout (bytes). syT declared 26 rows; reads from lanes 26..31
// overrun into sAb/sbias (read-only after staging; results masked) - by design.
#define OFF_SRES  0        // 256*40*2  = 20480
#define OFF_SYT   20480    // 26*264*2  = 13728
#define OFF_SAB   34208    // 32*32*2   = 2048
#define OFF_SBIAS 36256    // 4*256*4   = 4096
#define SMEM_BYTES 40352   // <= 40960 -> 4 WGs/CU

// ---- pack the four 256x256 fp32 w into bf16 MFMA A-fragment order ----
// wp[((blk*4+wv)*16+k)*1024 + pair*512 + lane*8 + e]
//   = w_blk[wv*64+pair*32+(lane&31)][k*16+(lane>>5)*8+e]
__global__ void convert_w(const float* __restrict__ w1, const float* __restrict__ w2,
                          const float* __restrict__ w3, const float* __restrict__ w4,
                          bf16* __restrict__ wp) {
    const int gid = blockIdx.x * 256 + threadIdx.x;   // 0..32767
    const int e8  = gid * 8;                          // linear over 4*65536 elems
    const int blk = e8 >> 16;
    const int off = e8 & 65535;
    const int row = off >> 8;
    const int col = off & 255;
    const float* src = (blk == 0) ? w1 : (blk == 1) ? w2 : (blk == 2) ? w3 : w4;
    const float4 f0 = *(const float4*)(src + off);        // coalesced reads
    const float4 f1 = *(const float4*)(src + off + 4);
    bf16x8 o;
    o[0] = (bf16)f0.x; o[1] = (bf16)f0.y; o[2] = (bf16)f0.z; o[3] = (bf16)f0.w;
    o[4] = (bf16)f1.x; o[5] = (bf16)f1.y; o[6] = (bf16)f1.z; o[7] = (bf16)f1.w;
    const int wv = row >> 6, pair = (row >> 5) & 1, l31 = row & 31;
    const int k = col >> 4, lh = (col >> 3) & 1;
    wp += (((size_t)(blk * 4 + wv) * 16 + k) * 1024) + pair * 512 + (lh * 32 + l31) * 8;
    *(bf16x8*)wp = o;
}

#define MFMA(A, B, C) __builtin_amdgcn_mfma_f32_32x32x16_bf16(A, B, C, 0, 0, 0)

__global__ __launch_bounds__(256, 4) void ode_mfma(
    const float* __restrict__ x, const float* __restrict__ Amat,
    const bf16* __restrict__ wp,
    const float* __restrict__ b1, const float* __restrict__ b2,
    const float* __restrict__ b3, const float* __restrict__ b4,
    float* __restrict__ out)
{
    __shared__ __attribute__((aligned(16))) char smem[SMEM_BYTES];
    bf16*  sres  = (bf16*)(smem + OFF_SRES);    // [c][RS]
    bf16*  syT   = (bf16*)(smem + OFF_SYT);     // [v][YS]
    bf16*  sAb   = (bf16*)(smem + OFF_SAB);     // [v][32]
    float* sbias = (float*)(smem + OFF_SBIAS);  // [4][CC]

    const int t    = blockIdx.x;
    const int n    = blockIdx.y;
    const int tid  = threadIdx.x;
    const int wave = tid >> 6;
    const int lane = tid & 63;
    const int lh   = lane >> 5;
    const int l31  = lane & 31;
    const int o0   = wave * 64;

    // ---- blk0 w-prefetch: no LDS dependency, issue before all staging so the
    //      16 global loads complete under the staging phase + barrier. ----
    bf16x8 wA[8], wB[8];
    {
        const bf16* wb0 = wp + ((size_t)wave * 16) * 1024 + lane * 8;
        #pragma unroll
        for (int q = 0; q < 8; ++q) {
            wA[q] = *(const bf16x8*)(wb0 + q * 1024);
            wB[q] = *(const bf16x8*)(wb0 + q * 1024 + 512);
        }
    }

    // ---- stage biases (coalesced) ----
    sbias[0 * CC + tid] = b1[tid];
    sbias[1 * CC + tid] = b2[tid];
    sbias[2 * CC + tid] = b3[tid];
    sbias[3 * CC + tid] = b4[tid];

    // ---- stage A, zero-padded to 32x32 ----
    for (int i = tid; i < 32 * 32; i += 256) {
        const int v = i >> 5, u = i & 31;
        sAb[i] = (v < VV && u < VV) ? (bf16)Amat[v * VV + u] : (bf16)0.f;
    }

    // ---- stage x slab (mostly-coalesced scalar; odd t breaks 8B alignment) ----
    {
        const float* xb = x + ((size_t)n * CC * TT + t) * VV;  // + c*T*V + v
        for (int i = tid; i < CC * VV; i += 256) {
            const int c = i / VV;
            const int v = i - c * VV;
            sres[c * RS + v] = (bf16)xb[(size_t)c * TT * VV + v];
        }
        #pragma unroll
        for (int u = VV; u < 32; ++u) sres[tid * RS + u] = (bf16)0.f;  // tid == c
    }
    __syncthreads();

    // A-matrix B-fragments are constant across blocks: hoist.
    const bf16x8 bfA0 = *(const bf16x8*)&sAb[l31 * 32 + lh * 8];
    const bf16x8 bfA1 = *(const bf16x8*)&sAb[l31 * 32 + 16 + lh * 8];

    for (int blk = 0; blk < 4; ++blk) {
        // ===== Phase A: yT[v][c] = sum_u res[c][u] * A[v][u]; 2 c-tiles/wave =====
        // sres rows read here are wave-local (rows [wave*64, wave*64+64) were
        // written by this wave's own epilogue): no barrier needed for sres.
        #pragma unroll
        for (int i = 0; i < 2; ++i) {
            const int ct = wave * 2 + i;
            const bf16x8 af0 = *(const bf16x8*)&sres[(ct * 32 + l31) * RS + lh * 8];
            const bf16x8 af1 = *(const bf16x8*)&sres[(ct * 32 + l31) * RS + 16 + lh * 8];
            f32x16 d = {};
            d = MFMA(af0, bfA0, d);
            d = MFMA(af1, bfA1, d);
            // D: col v = l31, row c = ct*32 + (reg&3) + 8*(reg>>2) + 4*lh
            if (l31 < VV) {
                #pragma unroll
                for (int g = 0; g < 4; ++g) {
                    bf16x4 p;
                    p[0] = (bf16)d[4 * g];     p[1] = (bf16)d[4 * g + 1];
                    p[2] = (bf16)d[4 * g + 2]; p[3] = (bf16)d[4 * g + 3];
                    *(bf16x4*)&syT[l31 * YS + ct * 32 + 8 * g + 4 * lh] = p;
                }
            }
        }
        __syncthreads();   // barrier1: syT writes -> k-loop reads

        // ===== Phase G: out[o][v] = relu(sum_c w[o,c] y[c][v] + b[o] + res[o][v]) =====
        // Software pipeline: w rotated depth-8 (prefetched last iter), y depth-4.
        const bf16* wbase = wp + ((size_t)(blk * 4 + wave) * 16) * 1024 + lane * 8;

        f32x16 acc0 = {}, acc1 = {};
        bf16x8 yv[4];
        #pragma unroll
        for (int q = 0; q < 4; ++q)
            yv[q] = *(const bf16x8*)&syT[l31 * YS + q * 16 + lh * 8];

        __builtin_amdgcn_s_setprio(1);
        #pragma unroll
        for (int k = 0; k < 16; ++k) {
            const bf16x8 a0 = wA[k & 7];
            const bf16x8 a1 = wB[k & 7];
            const bf16x8 y0 = yv[k & 3];
            if (k < 8) {    // refill slot k with k-step k+8 (static indices)
                wA[k] = *(const bf16x8*)(wbase + (k + 8) * 1024);
                wB[k] = *(const bf16x8*)(wbase + (k + 8) * 1024 + 512);
            }
            if (k < 12)
                yv[k & 3] = *(const bf16x8*)&syT[l31 * YS + (k + 4) * 16 + lh * 8];
            acc0 = MFMA(a0, y0, acc0);
            acc1 = MFMA(a1, y0, acc1);
        }
        __builtin_amdgcn_s_setprio(0);
        __syncthreads();   // barrier2: syT reads done -> next Phase A may write.

        // ---- prefetch next block's w (8 slots): L2 latency hides under the
        //      epilogue + next Phase A; covers iters 0..7 of next k-loop ----
        if (blk < 3) {
            const bf16* wn = wp + ((size_t)((blk + 1) * 4 + wave) * 16) * 1024 + lane * 8;
            #pragma unroll
            for (int q = 0; q < 8; ++q) {
                wA[q] = *(const bf16x8*)(wn + q * 1024);
                wB[q] = *(const bf16x8*)(wn + q * 1024 + 512);
            }
        }

        const int v = l31;
        #define EPILOGUE(ACC, OT)                                                   \
            _Pragma("unroll")                                                       \
            for (int g = 0; g < 4; ++g) {                                           \
                const int ob = o0 + (OT) * 32 + 8 * g + 4 * lh;                     \
                const float4 bq = *(const float4*)&sbias[blk * CC + ob];            \
                _Pragma("unroll")                                                   \
                for (int r = 0; r < 4; ++r) {                                       \
                    const int o = ob + r;                                           \
                    float val = ACC[4 * g + r] + ((const float*)&bq)[r]             \
                              + (float)sres[o * RS + v];                            \
                    val = fmaxf(val, 0.f);                                          \
                    if (v < VV) {                                                   \
                        if (blk < 3) sres[o * RS + v] = (bf16)val;                  \
                        else out[(((size_t)n * CC + o) * TT + t) * VV + v] = val;   \
                    }                                                               \
                }                                                                   \
            }
        EPILOGUE(acc0, 0)
        EPILOGUE(acc1, 1)
        #undef EPILOGUE
    }
}

extern "C" void kernel_launch(void* const* d_in, const int* in_sizes, int n_in,
                              void* d_out, int out_size, void* d_ws, size_t ws_size,
                              hipStream_t stream) {
    const float* x  = (const float*)d_in[1];
    const float* A  = (const float*)d_in[2];
    const float* w1 = (const float*)d_in[3];
    const float* b1 = (const float*)d_in[4];
    const float* w2 = (const float*)d_in[5];
    const float* b2 = (const float*)d_in[6];
    const float* w3 = (const float*)d_in[7];
    const float* b3 = (const float*)d_in[8];
    const float* w4 = (const float*)d_in[9];
    const float* b4 = (const float*)d_in[10];
    float* out = (float*)d_out;
    bf16* wp = (bf16*)d_ws;   // 512 KB packed w fragments

    convert_w<<<128, 256, 0, stream>>>(w1, w2, w3, w4, wp);
    dim3 grid(TT, NN);        // one WG per (n,t) slab: 4096 WGs
    ode_mfma<<<grid, 256, 0, stream>>>(x, A, wp, b1, b2, b3, b4, out);
}

// Round 12
// 354.585 us; speedup vs baseline: 1.0962x; 1.0240x over previous
//
#include <hip/hip_runtime.h>
#include <math.h>

// N=64, C=256, T=64, V=25 graph-ODE, 4 fused blocks. bf16 MFMA 32x32x16.
// R7 (prev best, 181.5us): 2-phase, 4 waves x 64-o tiles, depth-4 w rotation.
// R6/R15: any extra per-wave state SPILLS at reported VGPR=64 -> per-wave
//     budget saturated at ~128 total regs (64 VGPR + ~64 AGPR) @ 4 waves/SIMD.
// R16: halve per-wave footprint: 512-thread WG, 8 waves x 32-o tiles.
//     Per wave: ONE f32x16 acc (16 AGPR), ONE w stream (wW[4]=16 VGPR),
//     1 Phase-A c-tile. ~75-90 regs/wave -> 5-6 waves/SIMD (vs 4).
//     Same LDS layout/barriers/fragment maps as R7; wave->work remap only.
#define NN 64
#define CC 256
#define TT 64
#define VV 25

typedef __bf16 bf16;
typedef __attribute__((ext_vector_type(8)))  __bf16 bf16x8;
typedef __attribute__((ext_vector_type(4)))  __bf16 bf16x4;
typedef __attribute__((ext_vector_type(16))) float  f32x16;

#define RS 40    // sres row stride (bf16): 80 B
#define YS 264   // syT row stride (bf16): 528 B

// Manual LDS layout (bytes). syT declared 26 rows; reads from lanes 26..31
// overrun into sAb/sbias (read-only after staging; results masked) - by design.
#define OFF_SRES  0        // 256*40*2  = 20480
#define OFF_SYT   20480    // 26*264*2  = 13728
#define OFF_SAB   34208    // 32*32*2   = 2048
#define OFF_SBIAS 36256    // 4*256*4   = 4096
#define SMEM_BYTES 40352   // <= 40960 -> 4 WGs/CU by LDS (32 waves ceiling)

// ---- pack the four 256x256 fp32 w into bf16 MFMA A-fragment order ----
// wp[((blk*4+wv)*16+k)*1024 + pair*512 + lane*8 + e]
//   = w_blk[wv*64+pair*32+(lane&31)][k*16+(lane>>5)*8+e]
__global__ void convert_w(const float* __restrict__ w1, const float* __restrict__ w2,
                          const float* __restrict__ w3, const float* __restrict__ w4,
                          bf16* __restrict__ wp) {
    const int gid = blockIdx.x * 256 + threadIdx.x;   // 0..32767
    const int e8  = gid * 8;                          // linear over 4*65536 elems
    const int blk = e8 >> 16;
    const int off = e8 & 65535;
    const int row = off >> 8;
    const int col = off & 255;
    const float* src = (blk == 0) ? w1 : (blk == 1) ? w2 : (blk == 2) ? w3 : w4;
    const float4 f0 = *(const float4*)(src + off);        // coalesced reads
    const float4 f1 = *(const float4*)(src + off + 4);
    bf16x8 o;
    o[0] = (bf16)f0.x; o[1] = (bf16)f0.y; o[2] = (bf16)f0.z; o[3] = (bf16)f0.w;
    o[4] = (bf16)f1.x; o[5] = (bf16)f1.y; o[6] = (bf16)f1.z; o[7] = (bf16)f1.w;
    const int wv = row >> 6, pair = (row >> 5) & 1, l31 = row & 31;
    const int k = col >> 4, lh = (col >> 3) & 1;
    wp += (((size_t)(blk * 4 + wv) * 16 + k) * 1024) + pair * 512 + (lh * 32 + l31) * 8;
    *(bf16x8*)wp = o;
}

#define MFMA(A, B, C) __builtin_amdgcn_mfma_f32_32x32x16_bf16(A, B, C, 0, 0, 0)

__global__ __launch_bounds__(512) void ode_mfma(
    const float* __restrict__ x, const float* __restrict__ Amat,
    const bf16* __restrict__ wp,
    const float* __restrict__ b1, const float* __restrict__ b2,
    const float* __restrict__ b3, const float* __restrict__ b4,
    float* __restrict__ out)
{
    __shared__ __attribute__((aligned(16))) char smem[SMEM_BYTES];
    bf16*  sres  = (bf16*)(smem + OFF_SRES);    // [c][RS]
    bf16*  syT   = (bf16*)(smem + OFF_SYT);     // [v][YS]
    bf16*  sAb   = (bf16*)(smem + OFF_SAB);     // [v][32]
    float* sbias = (float*)(smem + OFF_SBIAS);  // [4][CC]

    const int t    = blockIdx.x;
    const int n    = blockIdx.y;
    const int tid  = threadIdx.x;                // 0..511
    const int wave = tid >> 6;                   // 0..7: o-tile AND Phase-A c-tile
    const int lane = tid & 63;
    const int lh   = lane >> 5;
    const int l31  = lane & 31;
    const int o0   = wave * 32;                  // this wave's 32-o tile base

    // ---- blk0 w-prefetch: wave's (wv,pair) slice; no LDS dependency ----
    // wv = wave>>1 selects the 64-row group, pair = wave&1 the 32-row half.
    bf16x8 wW[4];
    {
        const bf16* wb0 = wp + ((size_t)(wave >> 1) * 16) * 1024
                             + (wave & 1) * 512 + lane * 8;
        #pragma unroll
        for (int q = 0; q < 4; ++q)
            wW[q] = *(const bf16x8*)(wb0 + q * 1024);
    }

    // ---- stage biases (coalesced, 512 threads cover 2x256 each half) ----
    if (tid < 256) {
        sbias[0 * CC + tid] = b1[tid];
        sbias[1 * CC + tid] = b2[tid];
    } else {
        const int c = tid - 256;
        sbias[2 * CC + c] = b3[c];
        sbias[3 * CC + c] = b4[c];
    }

    // ---- stage A, zero-padded to 32x32 ----
    for (int i = tid; i < 32 * 32; i += 512) {
        const int v = i >> 5, u = i & 31;
        sAb[i] = (v < VV && u < VV) ? (bf16)Amat[v * VV + u] : (bf16)0.f;
    }

    // ---- stage x slab ----
    {
        const float* xb = x + ((size_t)n * CC * TT + t) * VV;  // + c*T*V + v
        for (int i = tid; i < CC * VV; i += 512) {
            const int c = i / VV;
            const int v = i - c * VV;
            sres[c * RS + v] = (bf16)xb[(size_t)c * TT * VV + v];
        }
        if (tid < 256) {
            #pragma unroll
            for (int u = VV; u < 32; ++u) sres[tid * RS + u] = (bf16)0.f;  // tid == c
        }
    }
    __syncthreads();

    // A-matrix B-fragments are constant across blocks: hoist.
    const bf16x8 bfA0 = *(const bf16x8*)&sAb[l31 * 32 + lh * 8];
    const bf16x8 bfA1 = *(const bf16x8*)&sAb[l31 * 32 + 16 + lh * 8];

    for (int blk = 0; blk < 4; ++blk) {
        // ===== Phase A: yT[v][c] = sum_u res[c][u]*A[v][u]; 1 c-tile/wave =====
        // c-tile ct == wave == this wave's o-tile: sres rows [o0,o0+32) were
        // written by this wave's own epilogue -> wave-local, no sres barrier.
        {
            const int ct = wave;
            const bf16x8 af0 = *(const bf16x8*)&sres[(ct * 32 + l31) * RS + lh * 8];
            const bf16x8 af1 = *(const bf16x8*)&sres[(ct * 32 + l31) * RS + 16 + lh * 8];
            f32x16 d = {};
            d = MFMA(af0, bfA0, d);
            d = MFMA(af1, bfA1, d);
            // D: col v = l31, row c = ct*32 + (reg&3) + 8*(reg>>2) + 4*lh
            if (l31 < VV) {
                #pragma unroll
                for (int g = 0; g < 4; ++g) {
                    bf16x4 p;
                    p[0] = (bf16)d[4 * g];     p[1] = (bf16)d[4 * g + 1];
                    p[2] = (bf16)d[4 * g + 2]; p[3] = (bf16)d[4 * g + 3];
                    *(bf16x4*)&syT[l31 * YS + ct * 32 + 8 * g + 4 * lh] = p;
                }
            }
        }
        __syncthreads();   // barrier1: syT writes -> k-loop reads

        // ===== Phase G: out[o][v] = relu(sum_c w[o,c] y[c][v] + b + res) =====
        const bf16* wbase = wp + ((size_t)(blk * 4 + (wave >> 1)) * 16) * 1024
                               + (wave & 1) * 512 + lane * 8;

        f32x16 acc = {};
        bf16x8 yv[4];
        #pragma unroll
        for (int q = 0; q < 4; ++q)
            yv[q] = *(const bf16x8*)&syT[l31 * YS + q * 16 + lh * 8];

        __builtin_amdgcn_s_setprio(1);
        #pragma unroll
        for (int k = 0; k < 16; ++k) {
            const bf16x8 a0 = wW[k & 3];
            const bf16x8 y0 = yv[k & 3];
            if (k < 12) {   // static after full unroll -> registers, no scratch
                wW[k & 3] = *(const bf16x8*)(wbase + (k + 4) * 1024);
                yv[k & 3] = *(const bf16x8*)&syT[l31 * YS + (k + 4) * 16 + lh * 8];
            }
            acc = MFMA(a0, y0, acc);
        }
        __builtin_amdgcn_s_setprio(0);
        __syncthreads();   // barrier2: syT reads done -> next Phase A may write

        // ---- prefetch next block's w: L2 latency hides under the epilogue ----
        if (blk < 3) {
            const bf16* wn = wp + ((size_t)((blk + 1) * 4 + (wave >> 1)) * 16) * 1024
                                + (wave & 1) * 512 + lane * 8;
            #pragma unroll
            for (int q = 0; q < 4; ++q)
                wW[q] = *(const bf16x8*)(wn + q * 1024);
        }

        // ===== Epilogue: one 32x32 tile per wave =====
        const int v = l31;
        #pragma unroll
        for (int g = 0; g < 4; ++g) {
            const int ob = o0 + 8 * g + 4 * lh;
            const float4 bq = *(const float4*)&sbias[blk * CC + ob];
            #pragma unroll
            for (int r = 0; r < 4; ++r) {
                const int o = ob + r;
                float val = acc[4 * g + r] + ((const float*)&bq)[r]
                          + (float)sres[o * RS + v];
                val = fmaxf(val, 0.f);
                if (v < VV) {
                    if (blk < 3) sres[o * RS + v] = (bf16)val;
                    else out[(((size_t)n * CC + o) * TT + t) * VV + v] = val;
                }
            }
        }
    }
}

extern "C" void kernel_launch(void* const* d_in, const int* in_sizes, int n_in,
                              void* d_out, int out_size, void* d_ws, size_t ws_size,
                              hipStream_t stream) {
    const float* x  = (const float*)d_in[1];
    const float* A  = (const float*)d_in[2];
    const float* w1 = (const float*)d_in[3];
    const float* b1 = (const float*)d_in[4];
    const float* w2 = (const float*)d_in[5];
    const float* b2 = (const float*)d_in[6];
    const float* w3 = (const float*)d_in[7];
    const float* b3 = (const float*)d_in[8];
    const float* w4 = (const float*)d_in[9];
    const float* b4 = (const float*)d_in[10];
    float* out = (float*)d_out;
    bf16* wp = (bf16*)d_ws;   // 512 KB packed w fragments

    convert_w<<<128, 256, 0, stream>>>(w1, w2, w3, w4, wp);
    dim3 grid(TT, NN);        // one WG per (n,t) slab: 4096 WGs of 512
    ode_mfma<<<grid, 512, 0, stream>>>(x, A, wp, b1, b2, b3, b4, out);
}